// Round 1
// baseline (95.152 us; speedup 1.0000x reference)
//
#include <hip/hip_runtime.h>

typedef unsigned int u32;
typedef unsigned long long u64;

#define NEVENTS 268
#define MAXSP (NEVENTS * 8)

// ---------------- Threefry2x32-20 (exact JAX semantics) ----------------
__device__ __forceinline__ u32 rotl32(u32 v, int d) { return (v << d) | (v >> (32 - d)); }

__device__ __forceinline__ void tf(u32 k0, u32 k1, u32 x0, u32 x1, u32& o0, u32& o1) {
  u32 ks2 = k0 ^ k1 ^ 0x1BD11BDAu;
  x0 += k0; x1 += k1;
#define RND(r) { x0 += x1; x1 = rotl32(x1, r); x1 ^= x0; }
  RND(13) RND(15) RND(26) RND(6)
  x0 += k1;  x1 += ks2 + 1u;
  RND(17) RND(29) RND(16) RND(24)
  x0 += ks2; x1 += k0 + 2u;
  RND(13) RND(15) RND(26) RND(6)
  x0 += k0;  x1 += k1 + 3u;
  RND(17) RND(29) RND(16) RND(24)
  x0 += k1;  x1 += ks2 + 4u;
  RND(13) RND(15) RND(26) RND(6)
  x0 += ks2; x1 += k0 + 5u;
#undef RND
  o0 = x0; o1 = x1;
}

// partitionable random_bits, 32-bit, element with flat index `lo` (hi word = 0):
// bits = o0 ^ o1 of threefry(key, (0, lo))
__device__ __forceinline__ u32 tfx(u32 k0, u32 k1, u32 lo) {
  u32 a, b; tf(k0, k1, 0u, lo, a, b); return a ^ b;
}

// foldlike split: child j of key = threefry(key, (0, j)) full pair
__device__ __forceinline__ void tfsplit(u32 k0, u32 k1, u32 j, u32& c0, u32& c1) {
  tf(k0, k1, 0u, j, c0, c1);
}

// JAX randint(key, (), 0, span) for int32: k1,k2 = split(key); hi,lo = bits;
// m = (2^16 % span)^2 % span  (uint32 wraparound mul, exactly as lax);
// off = ((hi%span)*m + lo%span) % span   (all uint32 wraparound)
__device__ u32 jr_randint(u32 k0, u32 k1, u32 span) {
  u32 h0, h1, l0, l1;
  tfsplit(k0, k1, 0u, h0, h1);
  tfsplit(k0, k1, 1u, l0, l1);
  u32 hi = tfx(h0, h1, 0u);
  u32 lo = tfx(l0, l1, 0u);
  u32 m = 65536u % span;
  m = (m * m) % span;                 // uint32 wraparound mul == lax.mul
  return ((hi % span) * m + (lo % span)) % span;
}

// ---------------- digest ----------------
struct Digest {
  u32 has_wc;
  u32 wc_k0, wc_k1;   // lower-bits subkey of the last whole_chip randint
  u32 pin_mask;
  u32 n_sparse;
  u32 sp_idx[MAXSP];
  u32 sp_mask[MAXSP];
};
__device__ Digest g_dig;

// ---------------- kernel A: replicate the 268-event stream ----------------
__global__ void __launch_bounds__(512) eventsK(u32 n) {
  __shared__ u32 s_type[NEVENTS], s_a[NEVENTS], s_m0[NEVENTS], s_m1[NEVENTS];
  int i = threadIdx.x;
  if (i < NEVENTS) {
    // keys = split(key(42), 268): key_i = threefry((0,42), (0,i))
    u32 e0, e1; tf(0u, 42u, 0u, (u32)i, e0, e1);
    // k_type, k_apply = split(k)
    u32 t0, t1, a0, a1;
    tfsplit(e0, e1, 0u, t0, t1);
    tfsplit(e0, e1, 1u, a0, a1);
    // choice(k_type, 5, p=W): r = csum[-1]*(1-uniform); searchsorted left
    u32 ubits = tfx(t0, t1, 0u);
    float u = __uint_as_float((ubits >> 9) | 0x3f800000u) - 1.0f;
    float pc0 = 0.7398f;
    float pc1 = pc0 + 0.2256f;
    float pc2 = pc1 + 0.009f;
    float pc3 = pc2 + 0.0223f;
    float pc4 = pc3 + 0.0019f;
    float r = pc4 * (1.0f - u);
    int t = 0;
    if (pc0 < r) t = 1;
    if (pc1 < r) t = 2;
    if (pc2 < r) t = 3;
    if (pc3 < r) t = 4;

    u32 type = (u32)t, A = 0, M0 = 0, M1 = 0;
    if (t == 0) {                       // single_bit
      u32 k1a, k1b, k2a, k2b;
      tfsplit(a0, a1, 0u, k1a, k1b);
      tfsplit(a0, a1, 1u, k2a, k2b);
      u32 idx = jr_randint(k1a, k1b, n);
      u32 bit = jr_randint(k2a, k2b, 8u);
      A = idx; M0 = 1u << bit;
    } else if (t == 1) {                // byte_aligned
      u32 k1a, k1b, k2a, k2b, k3a, k3b;
      tfsplit(a0, a1, 0u, k1a, k1b);
      tfsplit(a0, a1, 1u, k2a, k2b);
      tfsplit(a0, a1, 2u, k3a, k3b);
      u32 idx = jr_randint(k1a, k1b, n);
      u32 nb  = 2u + jr_randint(k2a, k2b, 7u);
      // permutation(k3, 8): 1 round; key,subkey = split(k3); sort keys ascending (stable)
      u32 sk0, sk1; tfsplit(k3a, k3b, 1u, sk0, sk1);
      u32 keys[8]; u32 vals[8];
      for (int j = 0; j < 8; j++) { keys[j] = tfx(sk0, sk1, (u32)j); vals[j] = (u32)j; }
      for (int p = 1; p < 8; p++) {
        u32 kk = keys[p], vv = vals[p]; int q = p - 1;
        while (q >= 0 && keys[q] > kk) { keys[q+1] = keys[q]; vals[q+1] = vals[q]; q--; }
        keys[q+1] = kk; vals[q+1] = vv;
      }
      u32 mask = 0;
      for (u32 j = 0; j < nb; j++) mask |= (1u << vals[j]);
      A = idx; M0 = mask;
    } else if (t == 2) {                // non_byte (8-byte segment parity)
      u32 k1a, k1b, k2a, k2b, k3a, k3b;
      tfsplit(a0, a1, 0u, k1a, k1b);
      tfsplit(a0, a1, 1u, k2a, k2b);
      tfsplit(a0, a1, 2u, k3a, k3b);
      u32 start = jr_randint(k1a, k1b, n - 7u);
      u32 nb    = 2u + jr_randint(k2a, k2b, 63u);
      // bit_idxs = randint(k3,(64,),0,64): span 64 -> mult 0 -> lower bits only
      u32 l0, l1; tfsplit(k3a, k3b, 1u, l0, l1);
      u64 par = 0ull;
      for (u32 j = 0; j < nb; j++) par ^= (1ull << (tfx(l0, l1, j) & 63u));
      A = start; M0 = (u32)(par & 0xffffffffull); M1 = (u32)(par >> 32);
    } else if (t == 3) {                // whole_chip: store lower-bits subkey
      u32 l0, l1; tfsplit(a0, a1, 1u, l0, l1);
      M0 = l0; M1 = l1;
    } else {                            // pin
      u32 bit = jr_randint(a0, a1, 8u);
      M0 = 1u << bit;
    }
    s_type[i] = type; s_a[i] = A; s_m0[i] = M0; s_m1[i] = M1;
  }
  __syncthreads();
  if (threadIdx.x == 0) {
    int lastWC = -1;
    for (int j = 0; j < NEVENTS; j++) if (s_type[j] == 3u) lastWC = j;
    if (lastWC >= 0) { g_dig.has_wc = 1u; g_dig.wc_k0 = s_m0[lastWC]; g_dig.wc_k1 = s_m1[lastWC]; }
    else             { g_dig.has_wc = 0u; g_dig.wc_k0 = 0u; g_dig.wc_k1 = 0u; }
    u32 pin = 0, ns = 0;
    for (int j = lastWC + 1; j < NEVENTS; j++) {
      u32 ty = s_type[j];
      if (ty == 0u || ty == 1u) {
        g_dig.sp_idx[ns] = s_a[j]; g_dig.sp_mask[ns] = s_m0[j]; ns++;
      } else if (ty == 2u) {
        u64 par = ((u64)s_m1[j] << 32) | (u64)s_m0[j];
        for (int q = 0; q < 8; q++) {
          g_dig.sp_idx[ns] = s_a[j] + (u32)q;
          g_dig.sp_mask[ns] = (u32)((par >> (8 * q)) & 255ull);
          ns++;
        }
      } else if (ty == 4u) {
        pin ^= s_m0[j];
      }
    }
    g_dig.pin_mask = pin;
    g_dig.n_sparse = ns;
  }
}

// ---------------- kernel B: materialize base ^ pin ----------------
__global__ void __launch_bounds__(256) buildK(const int* __restrict__ x,
                                              int* __restrict__ out, u32 n) {
  u32 base = (blockIdx.x * 256u + threadIdx.x) * 4u;
  if (base + 3u >= n) return;
  u32 pin = g_dig.pin_mask;
  int4 v;
  if (g_dig.has_wc) {
    u32 k0 = g_dig.wc_k0, k1 = g_dig.wc_k1;
    v.x = (int)((tfx(k0, k1, base + 0u) & 255u) ^ pin);
    v.y = (int)((tfx(k0, k1, base + 1u) & 255u) ^ pin);
    v.z = (int)((tfx(k0, k1, base + 2u) & 255u) ^ pin);
    v.w = (int)((tfx(k0, k1, base + 3u) & 255u) ^ pin);
  } else {
    v = *reinterpret_cast<const int4*>(x + base);
    v.x ^= (int)pin; v.y ^= (int)pin; v.z ^= (int)pin; v.w ^= (int)pin;
  }
  *reinterpret_cast<int4*>(out + base) = v;
}

// ---------------- kernel C: sparse XOR scatter ----------------
__global__ void __launch_bounds__(512) sparseK(int* __restrict__ out) {
  u32 ns = g_dig.n_sparse;
  for (u32 j = threadIdx.x; j < ns; j += 512u)
    atomicXor((u32*)&out[g_dig.sp_idx[j]], g_dig.sp_mask[j]);
}

extern "C" void kernel_launch(void* const* d_in, const int* in_sizes, int n_in,
                              void* d_out, int out_size, void* d_ws, size_t ws_size,
                              hipStream_t stream) {
  const int* x = (const int*)d_in[0];
  int* out = (int*)d_out;
  u32 n = (u32)in_sizes[0];

  eventsK<<<1, 512, 0, stream>>>(n);
  u32 blocks = (n / 4u + 255u) / 256u;
  buildK<<<blocks, 256, 0, stream>>>(x, out, n);
  sparseK<<<1, 512, 0, stream>>>(out);
}

// Round 2
// 74.202 us; speedup vs baseline: 1.2823x; 1.2823x over previous
//
#include <hip/hip_runtime.h>

typedef unsigned int u32;
typedef unsigned long long u64;

#define NEVENTS 268

// ---------------- Threefry2x32-20 (exact JAX semantics) ----------------
__device__ __forceinline__ u32 rotl32(u32 v, int d) { return (v << d) | (v >> (32 - d)); }

__device__ __forceinline__ void tf(u32 k0, u32 k1, u32 x0, u32 x1, u32& o0, u32& o1) {
  u32 ks2 = k0 ^ k1 ^ 0x1BD11BDAu;
  x0 += k0; x1 += k1;
#define RND(r) { x0 += x1; x1 = rotl32(x1, r); x1 ^= x0; }
  RND(13) RND(15) RND(26) RND(6)
  x0 += k1;  x1 += ks2 + 1u;
  RND(17) RND(29) RND(16) RND(24)
  x0 += ks2; x1 += k0 + 2u;
  RND(13) RND(15) RND(26) RND(6)
  x0 += k0;  x1 += k1 + 3u;
  RND(17) RND(29) RND(16) RND(24)
  x0 += k1;  x1 += ks2 + 4u;
  RND(13) RND(15) RND(26) RND(6)
  x0 += ks2; x1 += k0 + 5u;
#undef RND
  o0 = x0; o1 = x1;
}

__device__ __forceinline__ u32 tfx(u32 k0, u32 k1, u32 lo) {
  u32 a, b; tf(k0, k1, 0u, lo, a, b); return a ^ b;
}
__device__ __forceinline__ void tfsplit(u32 k0, u32 k1, u32 j, u32& c0, u32& c1) {
  tf(k0, k1, 0u, j, c0, c1);
}
// JAX randint modular combine (uint32 wraparound algebra, exactly as lax)
__device__ __forceinline__ u32 combine(u32 hi, u32 lo, u32 span) {
  u32 m = 65536u % span;
  m = (m * m) % span;
  return ((hi % span) * m + (lo % span)) % span;
}

// ---------------- globals (fully rewritten every call -> deterministic) ----
__device__ u32 g_type[NEVENTS];
__device__ u32 g_w0[NEVENTS], g_w1[NEVENTS];          // wc subkey / pin mask
__device__ u32 g_spidx[NEVENTS * 8], g_spmask[NEVENTS * 8];
struct Dig { u32 has_wc, k0, k1, pin; int lastwc; };
__device__ Dig g_dig;

// ---------------- kernel A: one event per 64-lane block --------------------
__global__ void __launch_bounds__(64) eventsK(u32 n) {
  int e = blockIdx.x;
  int lane = threadIdx.x;

  // keys = split(key(42), 268): key_e = threefry((0,42),(0,e))
  u32 e0, e1; tf(0u, 42u, 0u, (u32)e, e0, e1);
  u32 t0, t1, a0, a1;
  tfsplit(e0, e1, 0u, t0, t1);
  tfsplit(e0, e1, 1u, a0, a1);

  // choice(k_type, 5, p=W)
  u32 ub = tfx(t0, t1, 0u);
  float u = __uint_as_float((ub >> 9) | 0x3f800000u) - 1.0f;
  float pc0 = 0.7398f;
  float pc1 = pc0 + 0.2256f;
  float pc2 = pc1 + 0.009f;
  float pc3 = pc2 + 0.0223f;
  float pc4 = pc3 + 0.0019f;
  float r = pc4 * (1.0f - u);
  int t = 0;
  if (pc0 < r) t = 1;
  if (pc1 < r) t = 2;
  if (pc2 < r) t = 3;
  if (pc3 < r) t = 4;

  u32 w0 = 0, w1 = 0;
  u32 slot_i[8], slot_m[8];
  for (int q = 0; q < 8; q++) { slot_i[q] = 0u; slot_m[q] = 0u; }

  if (t == 0) {                       // single_bit
    // lanes 0/1: hi/lo of idx (key split(a,0)); lanes 2/3: hi/lo of bit (split(a,1))
    u32 s1 = (u32)((lane >> 1) & 1), s0 = (u32)(lane & 1);
    u32 ka, kb, qa, qb;
    tfsplit(a0, a1, s1, ka, kb);
    tfsplit(ka, kb, s0, qa, qb);
    u32 bits = tfx(qa, qb, 0u);
    u32 hi_i = __shfl(bits, 0, 64), lo_i = __shfl(bits, 1, 64);
    u32 hi_b = __shfl(bits, 2, 64), lo_b = __shfl(bits, 3, 64);
    if (lane == 0) {
      u32 idx = combine(hi_i, lo_i, n);
      u32 bit = combine(hi_b, lo_b, 8u);
      slot_i[0] = idx; slot_m[0] = 1u << bit;
    }
  } else if (t == 1) {                // byte_aligned
    bool pk = (lane >= 8 && lane < 16);
    u32 s1 = pk ? 2u : (u32)((lane >> 1) & 1);
    u32 s0 = pk ? 1u : (u32)(lane & 1);
    u32 ct = pk ? (u32)(lane - 8) : 0u;
    u32 ka, kb, qa, qb;
    tfsplit(a0, a1, s1, ka, kb);
    tfsplit(ka, kb, s0, qa, qb);
    u32 bits = tfx(qa, qb, ct);
    u32 hi_i = __shfl(bits, 0, 64), lo_i = __shfl(bits, 1, 64);
    u32 hi_n = __shfl(bits, 2, 64), lo_n = __shfl(bits, 3, 64);
    u32 p[8];
    for (int j = 0; j < 8; j++) p[j] = __shfl(bits, 8 + j, 64);
    if (lane == 0) {
      u32 idx = combine(hi_i, lo_i, n);
      u32 nb  = 2u + combine(hi_n, lo_n, 7u);
      u32 keys[8], vals[8];
      for (int j = 0; j < 8; j++) { keys[j] = p[j]; vals[j] = (u32)j; }
      for (int pp = 1; pp < 8; pp++) {       // stable ascending (sort_key_val)
        u32 kk = keys[pp], vv = vals[pp]; int q = pp - 1;
        while (q >= 0 && keys[q] > kk) { keys[q+1] = keys[q]; vals[q+1] = vals[q]; q--; }
        keys[q+1] = kk; vals[q+1] = vv;
      }
      u32 mask = 0;
      for (u32 j = 0; j < nb; j++) mask |= (1u << vals[j]);
      slot_i[0] = idx; slot_m[0] = mask;
    }
  } else if (t == 2) {                // non_byte (8-byte segment parity)
    // phase 1: all 64 lanes -> one bit_idx draw each  (chain a->k3->subkey->tfx(lane))
    u32 ka, kb, qa, qb;
    tfsplit(a0, a1, 2u, ka, kb);
    tfsplit(ka, kb, 1u, qa, qb);
    u32 bbits = tfx(qa, qb, (u32)lane);
    // phase 2: lanes 0..3 -> hi/lo draws for start (split(a,0)) and nb (split(a,1))
    u32 s1 = (u32)((lane >> 1) & 1), s0 = (u32)(lane & 1);
    u32 ra, rb, sa, sb;
    tfsplit(a0, a1, s1, ra, rb);
    tfsplit(ra, rb, s0, sa, sb);
    u32 rbits = tfx(sa, sb, 0u);
    u32 hi_s = __shfl(rbits, 0, 64), lo_s = __shfl(rbits, 1, 64);
    u32 hi_n = __shfl(rbits, 2, 64), lo_n = __shfl(rbits, 3, 64);
    u32 nb = 2u + combine(hi_n, lo_n, 63u);   // uniform on all lanes
    u32 pos = bbits & 63u;
    u32 mlo = ((u32)lane < nb && pos < 32u)  ? (1u << pos)         : 0u;
    u32 mhi = ((u32)lane < nb && pos >= 32u) ? (1u << (pos - 32u)) : 0u;
    for (int d = 1; d < 64; d <<= 1) {
      mlo ^= __shfl_xor(mlo, d, 64);
      mhi ^= __shfl_xor(mhi, d, 64);
    }
    if (lane == 0) {
      u32 start = combine(hi_s, lo_s, n - 7u);
      for (int q = 0; q < 4; q++) { slot_i[q]   = start + (u32)q;      slot_m[q]   = (mlo >> (8*q)) & 255u; }
      for (int q = 0; q < 4; q++) { slot_i[4+q] = start + 4u + (u32)q; slot_m[4+q] = (mhi >> (8*q)) & 255u; }
    }
  } else if (t == 3) {                // whole_chip: keep lower-bits subkey
    u32 l0, l1; tfsplit(a0, a1, 1u, l0, l1);
    if (lane == 0) { w0 = l0; w1 = l1; }
  } else {                            // pin: randint(k_apply, 8) directly
    u32 qa, qb; tfsplit(a0, a1, (u32)(lane & 1), qa, qb);
    u32 bits = tfx(qa, qb, 0u);
    u32 hi = __shfl(bits, 0, 64), lo = __shfl(bits, 1, 64);
    if (lane == 0) w0 = 1u << combine(hi, lo, 8u);
  }

  if (lane == 0) {
    g_type[e] = (u32)t; g_w0[e] = w0; g_w1[e] = w1;
    for (int q = 0; q < 8; q++) {
      g_spidx[e*8 + q] = slot_i[q];
      g_spmask[e*8 + q] = slot_m[q];
    }
  }
}

// ---------------- kernel B: aggregate digest (parallel, tiny) --------------
__global__ void __launch_bounds__(512) aggK() {
  __shared__ int s_last;
  __shared__ u32 s_pin;
  if (threadIdx.x == 0) { s_last = -1; s_pin = 0u; }
  __syncthreads();
  int j = (int)threadIdx.x;
  u32 ty = (j < NEVENTS) ? g_type[j] : 0u;
  if (j < NEVENTS && ty == 3u) atomicMax(&s_last, j);
  __syncthreads();
  int lw = s_last;
  if (j < NEVENTS && ty == 4u && j > lw) atomicXor(&s_pin, g_w0[j]);
  __syncthreads();
  if (threadIdx.x == 0) {
    g_dig.lastwc = lw;
    g_dig.has_wc = (lw >= 0) ? 1u : 0u;
    g_dig.k0 = (lw >= 0) ? g_w0[lw] : 0u;
    g_dig.k1 = (lw >= 0) ? g_w1[lw] : 0u;
    g_dig.pin = s_pin;
  }
}

// ---------------- kernel C: materialize base ^ pin (8 elems/thread) --------
__global__ void __launch_bounds__(256) buildK(const int* __restrict__ x,
                                              int* __restrict__ out, u32 n) {
  u32 base = (blockIdx.x * 256u + threadIdx.x) * 8u;
  if (base + 7u >= n) return;
  u32 pin = g_dig.pin;
  int4 v0, v1;
  if (g_dig.has_wc) {
    u32 k0 = g_dig.k0, k1 = g_dig.k1;
    v0.x = (int)((tfx(k0, k1, base + 0u) & 255u) ^ pin);
    v0.y = (int)((tfx(k0, k1, base + 1u) & 255u) ^ pin);
    v0.z = (int)((tfx(k0, k1, base + 2u) & 255u) ^ pin);
    v0.w = (int)((tfx(k0, k1, base + 3u) & 255u) ^ pin);
    v1.x = (int)((tfx(k0, k1, base + 4u) & 255u) ^ pin);
    v1.y = (int)((tfx(k0, k1, base + 5u) & 255u) ^ pin);
    v1.z = (int)((tfx(k0, k1, base + 6u) & 255u) ^ pin);
    v1.w = (int)((tfx(k0, k1, base + 7u) & 255u) ^ pin);
  } else {
    v0 = *reinterpret_cast<const int4*>(x + base);
    v1 = *reinterpret_cast<const int4*>(x + base + 4);
    v0.x ^= (int)pin; v0.y ^= (int)pin; v0.z ^= (int)pin; v0.w ^= (int)pin;
    v1.x ^= (int)pin; v1.y ^= (int)pin; v1.z ^= (int)pin; v1.w ^= (int)pin;
  }
  *reinterpret_cast<int4*>(out + base)      = v0;
  *reinterpret_cast<int4*>(out + base + 4u) = v1;
}

// ---------------- kernel D: sparse XOR scatter ------------------------------
__global__ void __launch_bounds__(512) sparseK(int* __restrict__ out) {
  int lw = g_dig.lastwc;
  for (u32 s = threadIdx.x; s < NEVENTS * 8u; s += 512u) {
    if ((int)(s >> 3) > lw) {
      u32 m = g_spmask[s];
      if (m) atomicXor((u32*)&out[g_spidx[s]], m);
    }
  }
}

extern "C" void kernel_launch(void* const* d_in, const int* in_sizes, int n_in,
                              void* d_out, int out_size, void* d_ws, size_t ws_size,
                              hipStream_t stream) {
  const int* x = (const int*)d_in[0];
  int* out = (int*)d_out;
  u32 n = (u32)in_sizes[0];

  eventsK<<<NEVENTS, 64, 0, stream>>>(n);
  aggK<<<1, 512, 0, stream>>>();
  u32 blocks = (n / 8u + 255u) / 256u;
  buildK<<<blocks, 256, 0, stream>>>(x, out, n);
  sparseK<<<1, 512, 0, stream>>>(out);
}

// Round 3
// 66.565 us; speedup vs baseline: 1.4294x; 1.1147x over previous
//
#include <hip/hip_runtime.h>
#include <cstring>

typedef unsigned int u32;
typedef unsigned long long u64;

#define NEVENTS 268

// ---------------- Threefry2x32-20 (exact JAX semantics, host+device) --------
__host__ __device__ __forceinline__ u32 rotl32(u32 v, int d) { return (v << d) | (v >> (32 - d)); }

__host__ __device__ __forceinline__ void tf(u32 k0, u32 k1, u32 x0, u32 x1, u32& o0, u32& o1) {
  u32 ks2 = k0 ^ k1 ^ 0x1BD11BDAu;
  x0 += k0; x1 += k1;
#define RND(r) { x0 += x1; x1 = rotl32(x1, r); x1 ^= x0; }
  RND(13) RND(15) RND(26) RND(6)
  x0 += k1;  x1 += ks2 + 1u;
  RND(17) RND(29) RND(16) RND(24)
  x0 += ks2; x1 += k0 + 2u;
  RND(13) RND(15) RND(26) RND(6)
  x0 += k0;  x1 += k1 + 3u;
  RND(17) RND(29) RND(16) RND(24)
  x0 += k1;  x1 += ks2 + 4u;
  RND(13) RND(15) RND(26) RND(6)
  x0 += ks2; x1 += k0 + 5u;
#undef RND
  o0 = x0; o1 = x1;
}

__host__ __device__ __forceinline__ u32 tfx(u32 k0, u32 k1, u32 lo) {
  u32 a, b; tf(k0, k1, 0u, lo, a, b); return a ^ b;
}
__host__ __device__ __forceinline__ void tfsplit(u32 k0, u32 k1, u32 j, u32& c0, u32& c1) {
  tf(k0, k1, 0u, j, c0, c1);
}
// JAX randint modular combine (uint32 wraparound algebra, exactly as lax)
__host__ __device__ __forceinline__ u32 combine(u32 hi, u32 lo, u32 span) {
  u32 m = 65536u % span;
  m = (m * m) % span;                 // uint32 wraparound mul == lax.mul
  return ((hi % span) * m + (lo % span)) % span;
}
static u32 h_randint(u32 k0, u32 k1, u32 span) {
  u32 h0, h1, l0, l1;
  tfsplit(k0, k1, 0u, h0, h1);
  tfsplit(k0, k1, 1u, l0, l1);
  return combine(tfx(h0, h1, 0u), tfx(l0, l1, 0u), span);
}

// ---------------- host digest of the 268-event stream -----------------------
struct HostDigest {
  int lastwc;
  u32 wk0, wk1, pin;
  int ns;
  u32 sidx[NEVENTS * 8];
  u32 smsk[NEVENTS * 8];
};

static void addSparse(HostDigest& D, u32 idx, u32 msk) {
  if (!msk) return;
  for (int j = 0; j < D.ns; j++)
    if (D.sidx[j] == idx) { D.smsk[j] ^= msk; return; }
  D.sidx[D.ns] = idx; D.smsk[D.ns] = msk; D.ns++;
}

static void computeDigest(u32 n, HostDigest& D) {
  int types[NEVENTS]; u32 A[NEVENTS], M0[NEVENTS], M1[NEVENTS];
  const float pc0 = 0.7398f;
  const float pc1 = pc0 + 0.2256f;
  const float pc2 = pc1 + 0.009f;
  const float pc3 = pc2 + 0.0223f;
  const float pc4 = pc3 + 0.0019f;

  for (int e = 0; e < NEVENTS; e++) {
    // keys = split(key(42), 268): key_e = threefry((0,42),(0,e))
    u32 e0, e1; tf(0u, 42u, 0u, (u32)e, e0, e1);
    u32 t0, t1, a0, a1;
    tfsplit(e0, e1, 0u, t0, t1);
    tfsplit(e0, e1, 1u, a0, a1);
    // choice(k_type, 5, p=W): plain IEEE single sub/mul — bit-identical to device
    u32 ub = tfx(t0, t1, 0u);
    float u; u32 fb = (ub >> 9) | 0x3f800000u; memcpy(&u, &fb, 4); u -= 1.0f;
    float r = pc4 * (1.0f - u);
    int t = 0;
    if (pc0 < r) t = 1;
    if (pc1 < r) t = 2;
    if (pc2 < r) t = 3;
    if (pc3 < r) t = 4;
    types[e] = t; A[e] = 0; M0[e] = 0; M1[e] = 0;

    if (t == 0) {                       // single_bit
      u32 k1a, k1b, k2a, k2b;
      tfsplit(a0, a1, 0u, k1a, k1b);
      tfsplit(a0, a1, 1u, k2a, k2b);
      A[e] = h_randint(k1a, k1b, n);
      M0[e] = 1u << h_randint(k2a, k2b, 8u);
    } else if (t == 1) {                // byte_aligned
      u32 k1a, k1b, k2a, k2b, k3a, k3b;
      tfsplit(a0, a1, 0u, k1a, k1b);
      tfsplit(a0, a1, 1u, k2a, k2b);
      tfsplit(a0, a1, 2u, k3a, k3b);
      A[e] = h_randint(k1a, k1b, n);
      u32 nb = 2u + h_randint(k2a, k2b, 7u);
      // permutation(k3, 8): subkey = split(k3)[1]; stable-sort 8 draws ascending
      u32 sk0, sk1; tfsplit(k3a, k3b, 1u, sk0, sk1);
      u32 keys[8], vals[8];
      for (int j = 0; j < 8; j++) { keys[j] = tfx(sk0, sk1, (u32)j); vals[j] = (u32)j; }
      for (int p = 1; p < 8; p++) {
        u32 kk = keys[p], vv = vals[p]; int q = p - 1;
        while (q >= 0 && keys[q] > kk) { keys[q+1] = keys[q]; vals[q+1] = vals[q]; q--; }
        keys[q+1] = kk; vals[q+1] = vv;
      }
      u32 mask = 0;
      for (u32 j = 0; j < nb; j++) mask |= (1u << vals[j]);
      M0[e] = mask;
    } else if (t == 2) {                // non_byte: 8-byte segment bit parity
      u32 k1a, k1b, k2a, k2b, k3a, k3b;
      tfsplit(a0, a1, 0u, k1a, k1b);
      tfsplit(a0, a1, 1u, k2a, k2b);
      tfsplit(a0, a1, 2u, k3a, k3b);
      A[e] = h_randint(k1a, k1b, n - 7u);
      u32 nb = 2u + h_randint(k2a, k2b, 63u);
      u32 l0, l1; tfsplit(k3a, k3b, 1u, l0, l1);   // span 64 -> lower-bits only
      u64 par = 0ull;
      for (u32 j = 0; j < nb; j++) par ^= (1ull << (tfx(l0, l1, j) & 63u));
      M0[e] = (u32)(par & 0xffffffffull); M1[e] = (u32)(par >> 32);
    } else if (t == 3) {                // whole_chip: keep lower-bits subkey
      u32 l0, l1; tfsplit(a0, a1, 1u, l0, l1);
      M0[e] = l0; M1[e] = l1;
    } else {                            // pin
      M0[e] = 1u << h_randint(a0, a1, 8u);
    }
  }

  int lw = -1;
  for (int e = 0; e < NEVENTS; e++) if (types[e] == 3) lw = e;
  D.lastwc = lw;
  D.wk0 = (lw >= 0) ? M0[lw] : 0u;
  D.wk1 = (lw >= 0) ? M1[lw] : 0u;
  D.pin = 0u; D.ns = 0;
  for (int e = lw + 1; e < NEVENTS; e++) {
    int t = types[e];
    if (t == 0 || t == 1) addSparse(D, A[e], M0[e]);
    else if (t == 2) {
      u64 par = ((u64)M1[e] << 32) | (u64)M0[e];
      for (int q = 0; q < 8; q++) addSparse(D, A[e] + (u32)q, (u32)((par >> (8*q)) & 255ull));
    } else if (t == 4) D.pin ^= M0[e];
  }
}

// ---------------- kernel: whole-chip regen ^ pin (8 elems/thread) -----------
__global__ void __launch_bounds__(256) buildGen(int* __restrict__ out, u32 n,
                                                u32 k0, u32 k1, u32 pin) {
  u32 base = (blockIdx.x * 256u + threadIdx.x) * 8u;
  if (base >= n) return;
  if (base + 8u <= n) {
    int4 v0, v1;
    v0.x = (int)((tfx(k0, k1, base + 0u) & 255u) ^ pin);
    v0.y = (int)((tfx(k0, k1, base + 1u) & 255u) ^ pin);
    v0.z = (int)((tfx(k0, k1, base + 2u) & 255u) ^ pin);
    v0.w = (int)((tfx(k0, k1, base + 3u) & 255u) ^ pin);
    v1.x = (int)((tfx(k0, k1, base + 4u) & 255u) ^ pin);
    v1.y = (int)((tfx(k0, k1, base + 5u) & 255u) ^ pin);
    v1.z = (int)((tfx(k0, k1, base + 6u) & 255u) ^ pin);
    v1.w = (int)((tfx(k0, k1, base + 7u) & 255u) ^ pin);
    *reinterpret_cast<int4*>(out + base)      = v0;
    *reinterpret_cast<int4*>(out + base + 4u) = v1;
  } else {
    for (u32 j = base; j < n; j++) out[j] = (int)((tfx(k0, k1, j) & 255u) ^ pin);
  }
}

// ---------------- kernel: copy x ^ pin (no whole-chip case) -----------------
__global__ void __launch_bounds__(256) buildCopy(const int* __restrict__ x,
                                                 int* __restrict__ out, u32 n, u32 pin) {
  u32 base = (blockIdx.x * 256u + threadIdx.x) * 8u;
  if (base >= n) return;
  if (base + 8u <= n) {
    int4 v0 = *reinterpret_cast<const int4*>(x + base);
    int4 v1 = *reinterpret_cast<const int4*>(x + base + 4);
    v0.x ^= (int)pin; v0.y ^= (int)pin; v0.z ^= (int)pin; v0.w ^= (int)pin;
    v1.x ^= (int)pin; v1.y ^= (int)pin; v1.z ^= (int)pin; v1.w ^= (int)pin;
    *reinterpret_cast<int4*>(out + base)      = v0;
    *reinterpret_cast<int4*>(out + base + 4u) = v1;
  } else {
    for (u32 j = base; j < n; j++) out[j] = x[j] ^ (int)pin;
  }
}

// ---------------- kernel: sparse XOR list passed via kernarg ----------------
struct SpChunk { u32 cnt; u32 idx[256]; u32 msk[256]; };

__global__ void __launch_bounds__(256) sparseK(int* __restrict__ out, SpChunk c) {
  u32 j = threadIdx.x;
  if (j < c.cnt) out[c.idx[j]] ^= (int)c.msk[j];   // indices host-deduped: no atomics
}

extern "C" void kernel_launch(void* const* d_in, const int* in_sizes, int n_in,
                              void* d_out, int out_size, void* d_ws, size_t ws_size,
                              hipStream_t stream) {
  const int* x = (const int*)d_in[0];
  int* out = (int*)d_out;
  u32 n = (u32)in_sizes[0];

  HostDigest D;
  computeDigest(n, D);   // pure CPU arithmetic, deterministic, ~µs

  u32 blocks = (n + 2047u) / 2048u;   // 8 elems/thread, 256 threads/block
  if (D.lastwc >= 0)
    buildGen<<<blocks, 256, 0, stream>>>(out, n, D.wk0, D.wk1, D.pin);
  else
    buildCopy<<<blocks, 256, 0, stream>>>(x, out, n, D.pin);

  for (int off = 0; off < D.ns; off += 256) {
    SpChunk c;
    c.cnt = (u32)((D.ns - off) < 256 ? (D.ns - off) : 256);
    for (u32 j = 0; j < c.cnt; j++) { c.idx[j] = D.sidx[off + j]; c.msk[j] = D.smsk[off + j]; }
    sparseK<<<1, 256, 0, stream>>>(out, c);
  }
}